// Round 1
// baseline (1023.106 us; speedup 1.0000x reference)
//
#include <hip/hip_runtime.h>
#include <hip/hip_bf16.h>
#include <stdint.h>

#define EPSF 1e-12f

__device__ __forceinline__ float stable_s(float x) {
    // x+1 if x>=0 else 1/(1-x)
    return (x >= 0.0f) ? (x + 1.0f) : (1.0f / (1.0f - x));
}

// One block per row: sum stable_s over the row, gather target, write -log(pt).
__global__ __launch_bounds__(256) void stablemax_row_loss(
    const float* __restrict__ logits,
    const int* __restrict__ targets,
    float* __restrict__ row_loss,
    int C)
{
    const int row = blockIdx.x;
    const float* rp = logits + (size_t)row * (size_t)C;
    const int t = threadIdx.x;

    // Row base is always 4B-aligned; peel scalars up to 16B alignment.
    uintptr_t addr = (uintptr_t)rp;
    int lead = (int)(((16u - (unsigned)(addr & 15u)) & 15u) >> 2);
    if (lead > C) lead = C;
    const int nvec = (C - lead) >> 2;            // float4 count
    const int tail_start = lead + (nvec << 2);

    float sum = 0.0f;

    if (t < lead) sum += stable_s(rp[t]);

    const float4* vp = (const float4*)(rp + lead);
    for (int i = t; i < nvec; i += 256) {
        float4 v = vp[i];
        sum += stable_s(v.x);
        sum += stable_s(v.y);
        sum += stable_s(v.z);
        sum += stable_s(v.w);
    }

    const int ti = tail_start + t;
    if (ti < C) sum += stable_s(rp[ti]);

    // Wave (64-lane) shuffle reduce, then cross-wave via LDS.
    #pragma unroll
    for (int off = 32; off > 0; off >>= 1)
        sum += __shfl_down(sum, off, 64);

    __shared__ float wsum[4];
    const int lane = t & 63;
    const int wid  = t >> 6;
    if (lane == 0) wsum[wid] = sum;
    __syncthreads();

    if (t == 0) {
        float denom = wsum[0] + wsum[1] + wsum[2] + wsum[3];
        denom = fmaxf(denom, EPSF);
        const int tgt = targets[row];
        const float st = stable_s(rp[tgt]);     // row is hot in L1/L2
        float pt = st / denom;
        pt = fmaxf(pt, EPSF);
        row_loss[row] = -logf(pt);
    }
}

// Single-block mean over B row losses.
__global__ __launch_bounds__(256) void mean_reduce(
    const float* __restrict__ row_loss,
    float* __restrict__ out,
    int B)
{
    float sum = 0.0f;
    for (int i = threadIdx.x; i < B; i += 256)
        sum += row_loss[i];

    #pragma unroll
    for (int off = 32; off > 0; off >>= 1)
        sum += __shfl_down(sum, off, 64);

    __shared__ float wsum[4];
    const int lane = threadIdx.x & 63;
    const int wid  = threadIdx.x >> 6;
    if (lane == 0) wsum[wid] = sum;
    __syncthreads();

    if (threadIdx.x == 0)
        out[0] = (wsum[0] + wsum[1] + wsum[2] + wsum[3]) / (float)B;
}

extern "C" void kernel_launch(void* const* d_in, const int* in_sizes, int n_in,
                              void* d_out, int out_size, void* d_ws, size_t ws_size,
                              hipStream_t stream) {
    const float* logits  = (const float*)d_in[0];
    const int*   targets = (const int*)d_in[1];

    const int B = in_sizes[1];                 // 4096 rows
    const int C = in_sizes[0] / B;             // 50257 classes

    float* row_loss = (float*)d_ws;            // B floats of scratch
    float* out      = (float*)d_out;

    stablemax_row_loss<<<B, 256, 0, stream>>>(logits, targets, row_loss, C);
    mean_reduce<<<1, 256, 0, stream>>>(row_loss, out, B);
}

// Round 2
// 1020.446 us; speedup vs baseline: 1.0026x; 1.0026x over previous
//
#include <hip/hip_runtime.h>
#include <hip/hip_bf16.h>
#include <stdint.h>

#define EPSF 1e-12f

// stable_s(x) = x+1 if x>=0 else 1/(1-x)  ==  (1+|x|)^(+1 or -1)
// v_rcp_f32 is ~1 ULP — the row sum (50257 terms, all in (0, +inf)) and the
// final -log(pt) (loss ~10.8, threshold 0.22) are insensitive to it.
__device__ __forceinline__ float stable_s_fast(float x) {
    float a = 1.0f + fabsf(x);              // abs is a free input modifier
    float r = __builtin_amdgcn_rcpf(a);     // v_rcp_f32
    return (x >= 0.0f) ? a : r;             // v_cmp + v_cndmask
}

// Precise version for the single per-row target gather.
__device__ __forceinline__ float stable_s(float x) {
    return (x >= 0.0f) ? (x + 1.0f) : (1.0f / (1.0f - x));
}

// One block per row: sum stable_s over the row, gather target, write -log(pt).
__global__ __launch_bounds__(256) void stablemax_row_loss(
    const float* __restrict__ logits,
    const int* __restrict__ targets,
    float* __restrict__ row_loss,
    int C)
{
    const int row = blockIdx.x;
    const float* rp = logits + (size_t)row * (size_t)C;
    const int t = threadIdx.x;

    // Row base is always 4B-aligned; peel scalars up to 16B alignment.
    uintptr_t addr = (uintptr_t)rp;
    int lead = (int)(((16u - (unsigned)(addr & 15u)) & 15u) >> 2);
    if (lead > C) lead = C;
    const int nvec = (C - lead) >> 2;            // float4 count
    const int tail_start = lead + (nvec << 2);

    float s0 = 0.0f, s1 = 0.0f, s2 = 0.0f, s3 = 0.0f;

    if (t < lead) s0 += stable_s_fast(rp[t]);

    const float4* vp = (const float4*)(rp + lead);

    // Unrolled x4: 4 independent loads in flight, 4 accumulators.
    int i = t;
    for (; i + 768 < nvec; i += 1024) {
        float4 a = vp[i];
        float4 b = vp[i + 256];
        float4 c = vp[i + 512];
        float4 d = vp[i + 768];
        s0 += stable_s_fast(a.x) + stable_s_fast(a.y) + stable_s_fast(a.z) + stable_s_fast(a.w);
        s1 += stable_s_fast(b.x) + stable_s_fast(b.y) + stable_s_fast(b.z) + stable_s_fast(b.w);
        s2 += stable_s_fast(c.x) + stable_s_fast(c.y) + stable_s_fast(c.z) + stable_s_fast(c.w);
        s3 += stable_s_fast(d.x) + stable_s_fast(d.y) + stable_s_fast(d.z) + stable_s_fast(d.w);
    }
    for (; i < nvec; i += 256) {
        float4 a = vp[i];
        s0 += stable_s_fast(a.x) + stable_s_fast(a.y) + stable_s_fast(a.z) + stable_s_fast(a.w);
    }

    const int ti = tail_start + t;
    if (ti < C) s1 += stable_s_fast(rp[ti]);

    float sum = (s0 + s1) + (s2 + s3);

    // Wave (64-lane) shuffle reduce, then cross-wave via LDS.
    #pragma unroll
    for (int off = 32; off > 0; off >>= 1)
        sum += __shfl_down(sum, off, 64);

    __shared__ float wsum[4];
    const int lane = t & 63;
    const int wid  = t >> 6;
    if (lane == 0) wsum[wid] = sum;
    __syncthreads();

    if (t == 0) {
        float denom = wsum[0] + wsum[1] + wsum[2] + wsum[3];
        denom = fmaxf(denom, EPSF);
        const int tgt = targets[row];
        const float st = stable_s(rp[tgt]);     // row is hot in L1/L2
        float pt = st / denom;
        pt = fmaxf(pt, EPSF);
        row_loss[row] = -logf(pt);
    }
}

// Single-block mean over B row losses.
__global__ __launch_bounds__(256) void mean_reduce(
    const float* __restrict__ row_loss,
    float* __restrict__ out,
    int B)
{
    float sum = 0.0f;
    for (int i = threadIdx.x; i < B; i += 256)
        sum += row_loss[i];

    #pragma unroll
    for (int off = 32; off > 0; off >>= 1)
        sum += __shfl_down(sum, off, 64);

    __shared__ float wsum[4];
    const int lane = threadIdx.x & 63;
    const int wid  = threadIdx.x >> 6;
    if (lane == 0) wsum[wid] = sum;
    __syncthreads();

    if (threadIdx.x == 0)
        out[0] = (wsum[0] + wsum[1] + wsum[2] + wsum[3]) / (float)B;
}

extern "C" void kernel_launch(void* const* d_in, const int* in_sizes, int n_in,
                              void* d_out, int out_size, void* d_ws, size_t ws_size,
                              hipStream_t stream) {
    const float* logits  = (const float*)d_in[0];
    const int*   targets = (const int*)d_in[1];

    const int B = in_sizes[1];                 // 4096 rows
    const int C = in_sizes[0] / B;             // 50257 classes

    float* row_loss = (float*)d_ws;            // B floats of scratch
    float* out      = (float*)d_out;

    stablemax_row_loss<<<B, 256, 0, stream>>>(logits, targets, row_loss, C);
    mean_reduce<<<1, 256, 0, stream>>>(row_loss, out, B);
}